// Round 9
// baseline (120.322 us; speedup 1.0000x reference)
//
#include <hip/hip_runtime.h>
#include <hip/hip_bf16.h>

#define NTOT 8192
#define NBSZ 4096
#define DDIM 256
#define NCHUNK 16
#define CHUNK_COLS 512
#define TILE_COLS 32
#define NT (CHUNK_COLS / TILE_COLS)
#define NCLASS 100

#define INV_T 14.285714285714286f
#define EPI_T 1.4285714285714286f
// base-2 folded: exp(logit) = exp2(dot*K1 + same*BIASS)
#define K1 20.609929155556076f      /* INV_T * log2(e) */
#define BIASS -2.0609929155556078f  /* -EPI_T * log2(e) */

typedef __attribute__((ext_vector_type(8))) __bf16 bf16x8;
typedef __attribute__((ext_vector_type(4))) float f32x4;

__device__ __forceinline__ unsigned short f2bf(float x) {
    union { float f; unsigned int u; } a; a.f = x;
    unsigned int r = a.u + 0x7fffu + ((a.u >> 16) & 1u);
    return (unsigned short)(r >> 16);
}

// K1: build bf16 contrast matrix B[8192][256] (view-major) + tiled labels; zero out[0].
__global__ __launch_bounds__(256) void prep_kernel(const float* __restrict__ feat,
                                                   const int* __restrict__ labels,
                                                   unsigned short* __restrict__ Bg,
                                                   int* __restrict__ labT,
                                                   float* __restrict__ out) {
    const int g = blockIdx.x * 256 + threadIdx.x;   // 8192 rows x 64 lanes
    const int row = g >> 6, t = g & 63;
    const int v = row >> 12, b = row & (NBSZ - 1);
    const float* src = feat + (size_t)(b * 2 + v) * DDIM + t * 4;
    f32x4 val = *(const f32x4*)src;
    ushort4 o;
    o.x = f2bf(val[0]); o.y = f2bf(val[1]); o.z = f2bf(val[2]); o.w = f2bf(val[3]);
    *(ushort4*)(Bg + (size_t)row * DDIM + t * 4) = o;
    if (t == 0) labT[row] = labels[b];
    if (g == 0) out[0] = 0.f;
}

// DMA one 32x256 bf16 tile into LDS (linear dest, source pre-swizzled so the
// read-side XOR sees conflict-free layout). 4 x 16B per thread.
__device__ __forceinline__ void stage_tile(const unsigned short* __restrict__ Bg,
                                           unsigned short* buf, int colBase, int tid) {
    #pragma unroll
    for (int it = 0; it < 4; ++it) {
        int c = it * 256 + tid;          // 16B-chunk index, 0..1023
        int brow = c >> 5, bc = c & 31;
        int sc = bc ^ (brow & 7);        // inverse swizzle on SOURCE
        const unsigned short* src = Bg + (size_t)(colBase + brow) * DDIM + sc * 8;
        __builtin_amdgcn_global_load_lds(
            (const __attribute__((address_space(1))) void*)src,
            (__attribute__((address_space(3))) void*)(buf + (size_t)c * 8),
            16, 0, 0);
    }
}

// Issue 16 MFMAs for one 64x32 sub-tile (acc zero-init inside).
__device__ __forceinline__ void do_mfma(f32x4 (&acc)[4][2], const unsigned short* bt,
                                        const bf16x8 (&afr)[4][8], int r16, int q) {
    #pragma unroll
    for (int m = 0; m < 4; ++m) { acc[m][0] = (f32x4)0.f; acc[m][1] = (f32x4)0.f; }
    #pragma unroll
    for (int ks = 0; ks < 8; ++ks) {
        const int cx = (ks * 4 + q) ^ (r16 & 7);
        bf16x8 bq0 = *(const bf16x8*)(bt + r16 * DDIM + cx * 8);
        bf16x8 bq1 = *(const bf16x8*)(bt + (16 + r16) * DDIM + cx * 8);
        #pragma unroll
        for (int m = 0; m < 4; ++m) {
            acc[m][0] = __builtin_amdgcn_mfma_f32_16x16x32_bf16(afr[m][ks], bq0, acc[m][0], 0, 0, 0);
            acc[m][1] = __builtin_amdgcn_mfma_f32_16x16x32_bf16(afr[m][ks], bq1, acc[m][1], 0, 0, 0);
        }
    }
}

// Epilogue for one tile's acc (runs while the NEXT tile's MFMAs are in flight).
__device__ __forceinline__ void do_epi(const f32x4 (&acc)[4][2], int tile,
                                       int colChunk, int rowBase,
                                       const int* labc_s, const int (&labrow)[4][4],
                                       float (&se)[4][4], float (&pd)[4][4],
                                       int r16, int q) {
    const int colBase = colChunk + tile * TILE_COLS;
    const int lc0 = labc_s[tile * TILE_COLS + r16];
    const int lc1 = labc_s[tile * TILE_COLS + 16 + r16];
    const bool diagT = ((unsigned)(colBase - rowBase)) < 64u;
    if (!diagT) {
        #pragma unroll
        for (int n = 0; n < 2; ++n) {
            const int lc = n ? lc1 : lc0;
            #pragma unroll
            for (int m = 0; m < 4; ++m)
                #pragma unroll
                for (int r = 0; r < 4; ++r) {
                    const bool same = (lc == labrow[m][r]);
                    float a = acc[m][n][r];
                    float t = fmaf(a, K1, same ? BIASS : 0.f);
                    se[m][r] += __builtin_amdgcn_exp2f(t);
                    pd[m][r] += same ? a : 0.f;
                }
        }
    } else {
        #pragma unroll
        for (int n = 0; n < 2; ++n) {
            const int lc = n ? lc1 : lc0;
            const int gcol = colBase + n * 16 + r16;
            #pragma unroll
            for (int m = 0; m < 4; ++m)
                #pragma unroll
                for (int r = 0; r < 4; ++r) {
                    const int grow = rowBase + m * 16 + q * 4 + r;
                    const bool same = (lc == labrow[m][r]);
                    const bool keep = (grow != gcol);
                    float a = acc[m][n][r];
                    float t = fmaf(a, K1, same ? BIASS : 0.f);
                    float e = __builtin_amdgcn_exp2f(t);
                    se[m][r] += keep ? e : 0.f;
                    pd[m][r] += (same && keep) ? a : 0.f;
                }
        }
    }
}

// K2: Gram + fused exp/pos sums, deferred-epilogue software pipeline.
// Grid (32 row-blocks, 16 chunks) = 512 blocks; wave owns 64 rows.
__global__ __launch_bounds__(256, 2) void supcon_main(
    const unsigned short* __restrict__ Bg, const int* __restrict__ labT,
    float* __restrict__ pSe, float* __restrict__ pPd)
{
    __shared__ alignas(16) unsigned short btile[2][TILE_COLS * DDIM];  // 2 x 16 KB
    __shared__ int labc_s[CHUNK_COLS];                                 // 2 KB

    const int tid = threadIdx.x;
    const int wid = tid >> 6;
    const int lane = tid & 63;
    const int q = lane >> 4;
    const int r16 = lane & 15;

    const int rowBase = blockIdx.x * 256 + wid * 64;   // wave owns 64 rows
    const int colChunk = blockIdx.y * CHUNK_COLS;

    labc_s[tid] = labT[colChunk + tid];
    labc_s[256 + tid] = labT[colChunk + 256 + tid];

    // A fragments: 64 rows x K=256 in registers (128 VGPR).
    bf16x8 afr[4][8];
    #pragma unroll
    for (int m = 0; m < 4; ++m) {
        const unsigned short* ap = Bg + (size_t)(rowBase + m * 16 + r16) * DDIM + q * 8;
        #pragma unroll
        for (int ks = 0; ks < 8; ++ks)
            afr[m][ks] = *(const bf16x8*)(ap + ks * 32);
    }
    int labrow[4][4];
    #pragma unroll
    for (int m = 0; m < 4; ++m)
        #pragma unroll
        for (int r = 0; r < 4; ++r)
            labrow[m][r] = labT[rowBase + m * 16 + q * 4 + r];

    float se[4][4], pd[4][4];
    #pragma unroll
    for (int m = 0; m < 4; ++m)
        #pragma unroll
        for (int r = 0; r < 4; ++r) { se[m][r] = 0.f; pd[m][r] = 0.f; }

    f32x4 accA[4][2], accB[4][2];

    // prologue: tiles 0,1 staged; tile0 MFMAs issued
    stage_tile(Bg, btile[0], colChunk, tid);
    __syncthreads();                                    // tile0 ready
    stage_tile(Bg, btile[1], colChunk + TILE_COLS, tid);
    do_mfma(accA, btile[0], afr, r16, q);
    __syncthreads();                                    // tile1 ready, btile0 reads done

    // steady state: mfma(t) overlaps epi(t-1); 2x unrolled for static acc ping/pong
    for (int t = 1; t + 1 < NT; t += 2) {
        stage_tile(Bg, btile[0], colChunk + (t + 1) * TILE_COLS, tid);
        do_mfma(accB, btile[1], afr, r16, q);
        do_epi(accA, t - 1, colChunk, rowBase, labc_s, labrow, se, pd, r16, q);
        __syncthreads();

        stage_tile(Bg, btile[1], colChunk + (t + 2) * TILE_COLS, tid);
        do_mfma(accA, btile[0], afr, r16, q);
        do_epi(accB, t, colChunk, rowBase, labc_s, labrow, se, pd, r16, q);
        __syncthreads();
    }
    // tail: tile NT-1
    do_mfma(accB, btile[1], afr, r16, q);
    do_epi(accA, NT - 2, colChunk, rowBase, labc_s, labrow, se, pd, r16, q);
    do_epi(accB, NT - 1, colChunk, rowBase, labc_s, labrow, se, pd, r16, q);

    // merge the 16 lanes (r16 bits) sharing each row
    #pragma unroll
    for (int mask = 1; mask <= 8; mask <<= 1)
        #pragma unroll
        for (int m = 0; m < 4; ++m)
            #pragma unroll
            for (int r = 0; r < 4; ++r) {
                se[m][r] += __shfl_xor(se[m][r], mask);
                pd[m][r] += __shfl_xor(pd[m][r], mask);
            }
    if (r16 == 0) {
        #pragma unroll
        for (int m = 0; m < 4; ++m) {
            const size_t o = (size_t)blockIdx.y * NTOT + rowBase + m * 16 + q * 4;
            f32x4 vs, vp;
            #pragma unroll
            for (int r = 0; r < 4; ++r) { vs[r] = se[m][r]; vp[r] = pd[m][r]; }
            *(f32x4*)(pSe + o) = vs;
            *(f32x4*)(pPd + o) = vp;
        }
    }
}

// K3: per-row loss (hist + chunk sums) + block partial + atomic out. 32 x 256.
__global__ __launch_bounds__(256) void finalize_kernel(
    const int* __restrict__ labT, const float* __restrict__ pSe,
    const float* __restrict__ pPd, float* __restrict__ out)
{
    __shared__ int hist[NCLASS];
    const int t = threadIdx.x;
    if (t < NCLASS) hist[t] = 0;
    __syncthreads();
    #pragma unroll
    for (int i = 0; i < NTOT / 256; ++i)
        atomicAdd(&hist[labT[i * 256 + t]], 1);
    __syncthreads();

    const int row = blockIdx.x * 256 + t;
    const int lab = labT[row];
    float se = 0.f, pdv = 0.f;
    #pragma unroll
    for (int ch = 0; ch < NCHUNK; ++ch) {
        se  += pSe[(size_t)ch * NTOT + row];
        pdv += pPd[(size_t)ch * NTOT + row];
    }
    const float pc = (float)(hist[lab] - 1);
    float loss = EPI_T + __logf(se) - INV_T * pdv / pc;

    #pragma unroll
    for (int mask = 1; mask < 64; mask <<= 1) loss += __shfl_xor(loss, mask);
    __shared__ float red[4];
    if ((t & 63) == 0) red[t >> 6] = loss;
    __syncthreads();
    if (t == 0)
        atomicAdd(out, (red[0] + red[1] + red[2] + red[3]) * (1.f / (float)NTOT));
}

extern "C" void kernel_launch(void* const* d_in, const int* in_sizes, int n_in,
                              void* d_out, int out_size, void* d_ws, size_t ws_size,
                              hipStream_t stream) {
    const float* feat = (const float*)d_in[0];
    const int* labels = (const int*)d_in[1];
    float* out = (float*)d_out;

    char* ws = (char*)d_ws;
    unsigned short* Bg = (unsigned short*)ws;                        // 4 MB
    int* labT = (int*)(ws + (4u << 20));                             // 32 KB
    float* pSe = (float*)(ws + (4u << 20) + (64u << 10));            // 512 KB
    float* pPd = (float*)(ws + (4u << 20) + (576u << 10));           // 512 KB

    prep_kernel<<<2048, 256, 0, stream>>>(feat, labels, Bg, labT, out);
    dim3 grid(32, NCHUNK);
    supcon_main<<<grid, 256, 0, stream>>>(Bg, labT, pSe, pPd);
    finalize_kernel<<<32, 256, 0, stream>>>(labT, pSe, pPd, out);
}

// Round 10
// 78.229 us; speedup vs baseline: 1.5381x; 1.5381x over previous
//
#include <hip/hip_runtime.h>
#include <hip/hip_bf16.h>

#define NTOT 8192
#define NBSZ 4096
#define DDIM 256
#define NCHUNK 16
#define CHUNK_COLS 512
#define TILE_COLS 32
#define NT (CHUNK_COLS / TILE_COLS)
#define NCLASS 100
#define CAP 192

#define INV_T 14.285714285714286f
#define EPI_T 1.4285714285714286f
#define K1 20.609929155556076f      /* INV_T * log2(e) */
#define ONE_M_2B 0.7603489635148818f /* 1 - 2^(-EPI_T*log2e) = 1 - e^(-EPI_T) */

typedef __attribute__((ext_vector_type(8))) __bf16 bf16x8;
typedef __attribute__((ext_vector_type(4))) float f32x4;

__device__ __forceinline__ unsigned short f2bf(float x) {
    union { float f; unsigned int u; } a; a.f = x;
    unsigned int r = a.u + 0x7fffu + ((a.u >> 16) & 1u);
    return (unsigned short)(r >> 16);
}

// K1: build bf16 contrast matrix B[8192][256] (view-major) + tiled labels; zero out[0].
__global__ __launch_bounds__(256) void prep_kernel(const float* __restrict__ feat,
                                                   const int* __restrict__ labels,
                                                   unsigned short* __restrict__ Bg,
                                                   int* __restrict__ labT,
                                                   float* __restrict__ out) {
    const int g = blockIdx.x * 256 + threadIdx.x;   // 8192 rows x 64 lanes
    const int row = g >> 6, t = g & 63;
    const int v = row >> 12, b = row & (NBSZ - 1);
    const float* src = feat + (size_t)(b * 2 + v) * DDIM + t * 4;
    f32x4 val = *(const f32x4*)src;
    ushort4 o;
    o.x = f2bf(val[0]); o.y = f2bf(val[1]); o.z = f2bf(val[2]); o.w = f2bf(val[3]);
    *(ushort4*)(Bg + (size_t)row * DDIM + t * 4) = o;
    if (t == 0) labT[row] = labels[b];
    if (g == 0) out[0] = 0.f;
}

// K2: per-class correction. Block c: deterministic member list, then dense
// MFMA X_c X_c^T over 16-row tiles -> C1 (same-label expsum, excl self),
// Pd (same-label dot sum, excl self), SelfE (exp2(K1*g_ii), bitwise = main's).
__global__ __launch_bounds__(256) void classcorr_kernel(
    const unsigned short* __restrict__ Bg, const int* __restrict__ labT,
    float* __restrict__ C1, float* __restrict__ Pd, float* __restrict__ SelfE)
{
    const int c = blockIdx.x;
    const int t = threadIdx.x;
    const int wid = t >> 6, lane = t & 63;
    const int q = lane >> 4, r16 = lane & 15;
    __shared__ unsigned short list[CAP];
    __shared__ int wsum[4];

    // count matches (thread t owns rows t+256k, coalesced per k)
    int cntLoc = 0;
    #pragma unroll
    for (int k = 0; k < 32; ++k) cntLoc += (labT[t + 256 * k] == c) ? 1 : 0;
    // wave inclusive scan
    int incl = cntLoc;
    #pragma unroll
    for (int d = 1; d < 64; d <<= 1) {
        int up = __shfl_up(incl, d);
        if (lane >= d) incl += up;
    }
    if (lane == 63) wsum[wid] = incl;
    __syncthreads();
    int off = incl - cntLoc;
    for (int w = 0; w < wid; ++w) off += wsum[w];
    const int cnt = wsum[0] + wsum[1] + wsum[2] + wsum[3];
    for (int k = 0; k < 32; ++k) {
        int row = t + 256 * k;
        if (labT[row] == c && off < CAP) list[off++] = (unsigned short)row;
    }
    __syncthreads();

    const int ntile = (cnt + 15) >> 4;
    for (int ti = wid; ti < ntile; ti += 4) {
        const int ilocB = ti * 16 + q * 4;
        const int ia = ti * 16 + r16;
        const int rowA = list[(ia < cnt) ? ia : 0];
        const unsigned short* ap = Bg + (size_t)rowA * DDIM + q * 8;
        bf16x8 af[8];
        #pragma unroll
        for (int ks = 0; ks < 8; ++ks) af[ks] = *(const bf16x8*)(ap + ks * 32);

        float c1a[4] = {0.f, 0.f, 0.f, 0.f};
        float pda[4] = {0.f, 0.f, 0.f, 0.f};
        for (int tj = 0; tj < ntile; ++tj) {
            const int jslot = tj * 16 + r16;
            const int rowB = list[(jslot < cnt) ? jslot : 0];
            const unsigned short* bp = Bg + (size_t)rowB * DDIM + q * 8;
            bf16x8 bf[8];
            #pragma unroll
            for (int ks = 0; ks < 8; ++ks) bf[ks] = *(const bf16x8*)(bp + ks * 32);
            f32x4 acc = (f32x4)0.f;
            #pragma unroll
            for (int ks = 0; ks < 8; ++ks)
                acc = __builtin_amdgcn_mfma_f32_16x16x32_bf16(af[ks], bf[ks], acc, 0, 0, 0);
            #pragma unroll
            for (int r = 0; r < 4; ++r) {
                const int islot = ilocB + r;
                const bool valid = (islot < cnt) && (jslot < cnt);
                const bool self = (islot == jslot);
                float a = acc[r];
                float e = __builtin_amdgcn_exp2f(a * K1);
                if (valid && self) SelfE[list[islot]] = e;
                c1a[r] += (valid && !self) ? e : 0.f;
                pda[r] += (valid && !self) ? a : 0.f;
            }
        }
        #pragma unroll
        for (int mask = 1; mask <= 8; mask <<= 1)
            #pragma unroll
            for (int r = 0; r < 4; ++r) {
                c1a[r] += __shfl_xor(c1a[r], mask);
                pda[r] += __shfl_xor(pda[r], mask);
            }
        if (r16 == 0) {
            #pragma unroll
            for (int r = 0; r < 4; ++r) {
                const int islot = ilocB + r;
                if (islot < cnt) {
                    C1[list[islot]] = c1a[r];
                    Pd[list[islot]] = pda[r];
                }
            }
        }
    }
}

// DMA one 32x256 bf16 tile into LDS (linear dest, source pre-swizzled so the
// read-side XOR sees conflict-free layout). 4 x 16B per thread.
__device__ __forceinline__ void stage_tile(const unsigned short* __restrict__ Bg,
                                           unsigned short* buf, int colBase, int tid) {
    #pragma unroll
    for (int it = 0; it < 4; ++it) {
        int c = it * 256 + tid;          // 16B-chunk index, 0..1023
        int brow = c >> 5, bc = c & 31;
        int sc = bc ^ (brow & 7);        // inverse swizzle on SOURCE
        const unsigned short* src = Bg + (size_t)(colBase + brow) * DDIM + sc * 8;
        __builtin_amdgcn_global_load_lds(
            (const __attribute__((address_space(1))) void*)src,
            (__attribute__((address_space(3))) void*)(buf + (size_t)c * 8),
            16, 0, 0);
    }
}

// K3: Gram + plain exp-sum over ALL columns (no labels, diag included).
// Grid (32 row-blocks, 16 chunks) = 512 blocks; wave owns 64 rows.
__global__ __launch_bounds__(256, 2) void supcon_main(
    const unsigned short* __restrict__ Bg, float* __restrict__ pSe)
{
    __shared__ alignas(16) unsigned short btile[2][TILE_COLS * DDIM];  // 2 x 16 KB

    const int tid = threadIdx.x;
    const int wid = tid >> 6;
    const int lane = tid & 63;
    const int q = lane >> 4;
    const int r16 = lane & 15;

    const int rowBase = blockIdx.x * 256 + wid * 64;   // wave owns 64 rows
    const int colChunk = blockIdx.y * CHUNK_COLS;

    // A fragments: 64 rows x K=256 in registers (128 VGPR).
    bf16x8 afr[4][8];
    #pragma unroll
    for (int m = 0; m < 4; ++m) {
        const unsigned short* ap = Bg + (size_t)(rowBase + m * 16 + r16) * DDIM + q * 8;
        #pragma unroll
        for (int ks = 0; ks < 8; ++ks)
            afr[m][ks] = *(const bf16x8*)(ap + ks * 32);
    }

    float se[4][4];
    #pragma unroll
    for (int m = 0; m < 4; ++m)
        #pragma unroll
        for (int r = 0; r < 4; ++r) se[m][r] = 0.f;

    stage_tile(Bg, btile[0], colChunk, tid);
    __syncthreads();   // drains vmcnt -> tile 0 ready

    for (int tile = 0; tile < NT; ++tile) {
        if (tile + 1 < NT)
            stage_tile(Bg, btile[(tile + 1) & 1], colChunk + (tile + 1) * TILE_COLS, tid);

        const unsigned short* bt = btile[tile & 1];
        f32x4 acc[4][2];
        #pragma unroll
        for (int m = 0; m < 4; ++m) { acc[m][0] = (f32x4)0.f; acc[m][1] = (f32x4)0.f; }

        __builtin_amdgcn_s_setprio(1);
        #pragma unroll
        for (int ks = 0; ks < 8; ++ks) {
            const int cx = (ks * 4 + q) ^ (r16 & 7);
            bf16x8 bq0 = *(const bf16x8*)(bt + r16 * DDIM + cx * 8);
            bf16x8 bq1 = *(const bf16x8*)(bt + (16 + r16) * DDIM + cx * 8);
            #pragma unroll
            for (int m = 0; m < 4; ++m) {
                acc[m][0] = __builtin_amdgcn_mfma_f32_16x16x32_bf16(afr[m][ks], bq0, acc[m][0], 0, 0, 0);
                acc[m][1] = __builtin_amdgcn_mfma_f32_16x16x32_bf16(afr[m][ks], bq1, acc[m][1], 0, 0, 0);
            }
        }
        __builtin_amdgcn_s_setprio(0);

        // thin epilogue: se += exp2(K1 * g) for every element
        #pragma unroll
        for (int n = 0; n < 2; ++n)
            #pragma unroll
            for (int m = 0; m < 4; ++m)
                #pragma unroll
                for (int r = 0; r < 4; ++r)
                    se[m][r] += __builtin_amdgcn_exp2f(acc[m][n][r] * K1);

        __syncthreads();   // drains DMA (next tile ready) + LDS reads done
    }

    // merge the 16 lanes (r16 bits) sharing each row
    #pragma unroll
    for (int mask = 1; mask <= 8; mask <<= 1)
        #pragma unroll
        for (int m = 0; m < 4; ++m)
            #pragma unroll
            for (int r = 0; r < 4; ++r)
                se[m][r] += __shfl_xor(se[m][r], mask);
    if (r16 == 0) {
        #pragma unroll
        for (int m = 0; m < 4; ++m) {
            const size_t o = (size_t)blockIdx.y * NTOT + rowBase + m * 16 + q * 4;
            f32x4 vs;
            #pragma unroll
            for (int r = 0; r < 4; ++r) vs[r] = se[m][r];
            *(f32x4*)(pSe + o) = vs;
        }
    }
}

// K4: per-row loss from (se_all, corrections) + block partial + atomic out.
__global__ __launch_bounds__(256) void finalize_kernel(
    const int* __restrict__ labT, const float* __restrict__ pSe,
    const float* __restrict__ C1, const float* __restrict__ Pd,
    const float* __restrict__ SelfE, float* __restrict__ out)
{
    __shared__ int hist[NCLASS];
    const int t = threadIdx.x;
    if (t < NCLASS) hist[t] = 0;
    __syncthreads();
    #pragma unroll
    for (int i = 0; i < NTOT / 256; ++i)
        atomicAdd(&hist[labT[i * 256 + t]], 1);
    __syncthreads();

    const int row = blockIdx.x * 256 + t;
    const int lab = labT[row];
    float se = 0.f;
    #pragma unroll
    for (int ch = 0; ch < NCHUNK; ++ch) se += pSe[(size_t)ch * NTOT + row];
    se = se - SelfE[row] - ONE_M_2B * C1[row];

    const float pc = (float)(hist[lab] - 1);
    float loss = EPI_T + __logf(se) - INV_T * Pd[row] / pc;

    #pragma unroll
    for (int mask = 1; mask < 64; mask <<= 1) loss += __shfl_xor(loss, mask);
    __shared__ float red[4];
    if ((t & 63) == 0) red[t >> 6] = loss;
    __syncthreads();
    if (t == 0)
        atomicAdd(out, (red[0] + red[1] + red[2] + red[3]) * (1.f / (float)NTOT));
}

extern "C" void kernel_launch(void* const* d_in, const int* in_sizes, int n_in,
                              void* d_out, int out_size, void* d_ws, size_t ws_size,
                              hipStream_t stream) {
    const float* feat = (const float*)d_in[0];
    const int* labels = (const int*)d_in[1];
    float* out = (float*)d_out;

    char* ws = (char*)d_ws;
    unsigned short* Bg = (unsigned short*)ws;                        // 4 MB
    int* labT = (int*)(ws + (4u << 20));                             // 32 KB
    float* pSe = (float*)(ws + (4u << 20) + (64u << 10));            // 512 KB
    float* C1v = (float*)(ws + (4u << 20) + (576u << 10));           // 32 KB
    float* Pdv = (float*)(ws + (4u << 20) + (640u << 10));           // 32 KB
    float* SEv = (float*)(ws + (4u << 20) + (704u << 10));           // 32 KB

    prep_kernel<<<2048, 256, 0, stream>>>(feat, labels, Bg, labT, out);
    classcorr_kernel<<<NCLASS, 256, 0, stream>>>(Bg, labT, C1v, Pdv, SEv);
    dim3 grid(32, NCHUNK);
    supcon_main<<<grid, 256, 0, stream>>>(Bg, pSe);
    finalize_kernel<<<32, 256, 0, stream>>>(labT, pSe, C1v, Pdv, SEv, out);
}

// Round 11
// 67.185 us; speedup vs baseline: 1.7909x; 1.1644x over previous
//
#include <hip/hip_runtime.h>
#include <hip/hip_bf16.h>

#define NTOT 8192
#define NBSZ 4096
#define DDIM 256
#define NCHUNK 16
#define CHUNK_COLS 512
#define TILE_COLS 32
#define NT (CHUNK_COLS / TILE_COLS)
#define NCLASS 100
#define CAP 192

#define INV_T 14.285714285714286f
#define EPI_T 1.4285714285714286f
#define K1 20.609929155556076f      /* INV_T * log2(e) */
#define ONE_M_2B 0.7603489635148818f /* 1 - e^(-EPI_T) */

typedef __attribute__((ext_vector_type(8))) __bf16 bf16x8;
typedef __attribute__((ext_vector_type(4))) float f32x4;

__device__ __forceinline__ unsigned short f2bf(float x) {
    union { float f; unsigned int u; } a; a.f = x;
    unsigned int r = a.u + 0x7fffu + ((a.u >> 16) & 1u);
    return (unsigned short)(r >> 16);
}

// K1: build bf16 contrast matrix B[8192][256] (view-major) + tiled labels; zero out[0].
__global__ __launch_bounds__(256) void prep_kernel(const float* __restrict__ feat,
                                                   const int* __restrict__ labels,
                                                   unsigned short* __restrict__ Bg,
                                                   int* __restrict__ labT,
                                                   float* __restrict__ out) {
    const int g = blockIdx.x * 256 + threadIdx.x;   // 8192 rows x 64 lanes
    const int row = g >> 6, t = g & 63;
    const int v = row >> 12, b = row & (NBSZ - 1);
    const float* src = feat + (size_t)(b * 2 + v) * DDIM + t * 4;
    f32x4 val = *(const f32x4*)src;
    ushort4 o;
    o.x = f2bf(val[0]); o.y = f2bf(val[1]); o.z = f2bf(val[2]); o.w = f2bf(val[3]);
    *(ushort4*)(Bg + (size_t)row * DDIM + t * 4) = o;
    if (t == 0) labT[row] = labels[b];
    if (g == 0) out[0] = 0.f;
}

// K2: per-class correction, parallelized: grid (class, 4); wave wid owns
// row-tile ti = blockIdx.y*4 + wid of the class member list. Dense MFMA
// X_c X_c^T -> C1 (same-label expsum excl self), Pd (same-label dot excl
// self), SelfE (exp2(K1*g_ii), bitwise identical to main's diag value).
__global__ __launch_bounds__(256) void classcorr_kernel(
    const unsigned short* __restrict__ Bg, const int* __restrict__ labT,
    float* __restrict__ C1, float* __restrict__ Pd, float* __restrict__ SelfE)
{
    const int c = blockIdx.x;
    const int t = threadIdx.x;
    const int wid = t >> 6, lane = t & 63;
    const int q = lane >> 4, r16 = lane & 15;
    __shared__ unsigned short list[CAP];
    __shared__ int wsum[4];

    // deterministic member-list build (identical across the 4 y-blocks)
    int cntLoc = 0;
    #pragma unroll
    for (int k = 0; k < 32; ++k) cntLoc += (labT[t + 256 * k] == c) ? 1 : 0;
    int incl = cntLoc;
    #pragma unroll
    for (int d = 1; d < 64; d <<= 1) {
        int up = __shfl_up(incl, d);
        if (lane >= d) incl += up;
    }
    if (lane == 63) wsum[wid] = incl;
    __syncthreads();
    int off = incl - cntLoc;
    for (int w = 0; w < wid; ++w) off += wsum[w];
    const int cnt = wsum[0] + wsum[1] + wsum[2] + wsum[3];
    for (int k = 0; k < 32; ++k) {
        int row = t + 256 * k;
        if (labT[row] == c && off < CAP) list[off++] = (unsigned short)row;
    }
    __syncthreads();

    const int ntile = (cnt + 15) >> 4;
    const int ti = blockIdx.y * 4 + wid;
    if (ti >= ntile) return;

    const int ilocB = ti * 16 + q * 4;
    const int ia = ti * 16 + r16;
    const int rowA = list[(ia < cnt) ? ia : 0];
    const unsigned short* ap = Bg + (size_t)rowA * DDIM + q * 8;
    bf16x8 af[8];
    #pragma unroll
    for (int ks = 0; ks < 8; ++ks) af[ks] = *(const bf16x8*)(ap + ks * 32);

    float c1a[4] = {0.f, 0.f, 0.f, 0.f};
    float pda[4] = {0.f, 0.f, 0.f, 0.f};

    // prefetch tj=0
    bf16x8 bfc[8], bfn[8];
    {
        const int j0 = r16;
        const unsigned short* bp = Bg + (size_t)list[(j0 < cnt) ? j0 : 0] * DDIM + q * 8;
        #pragma unroll
        for (int ks = 0; ks < 8; ++ks) bfc[ks] = *(const bf16x8*)(bp + ks * 32);
    }
    for (int tj = 0; tj < ntile; ++tj) {
        const int jslot = tj * 16 + r16;
        if (tj + 1 < ntile) {   // prefetch next tj under this tj's MFMAs
            const int jn = (tj + 1) * 16 + r16;
            const unsigned short* bp = Bg + (size_t)list[(jn < cnt) ? jn : 0] * DDIM + q * 8;
            #pragma unroll
            for (int ks = 0; ks < 8; ++ks) bfn[ks] = *(const bf16x8*)(bp + ks * 32);
        }
        f32x4 acc = (f32x4)0.f;
        #pragma unroll
        for (int ks = 0; ks < 8; ++ks)
            acc = __builtin_amdgcn_mfma_f32_16x16x32_bf16(af[ks], bfc[ks], acc, 0, 0, 0);
        #pragma unroll
        for (int r = 0; r < 4; ++r) {
            const int islot = ilocB + r;
            const bool valid = (islot < cnt) && (jslot < cnt);
            const bool self = (islot == jslot);
            float a = acc[r];
            float e = __builtin_amdgcn_exp2f(a * K1);
            if (valid && self) SelfE[list[islot]] = e;
            c1a[r] += (valid && !self) ? e : 0.f;
            pda[r] += (valid && !self) ? a : 0.f;
        }
        #pragma unroll
        for (int ks = 0; ks < 8; ++ks) bfc[ks] = bfn[ks];
    }
    #pragma unroll
    for (int mask = 1; mask <= 8; mask <<= 1)
        #pragma unroll
        for (int r = 0; r < 4; ++r) {
            c1a[r] += __shfl_xor(c1a[r], mask);
            pda[r] += __shfl_xor(pda[r], mask);
        }
    if (r16 == 0) {
        #pragma unroll
        for (int r = 0; r < 4; ++r) {
            const int islot = ilocB + r;
            if (islot < cnt) {
                C1[list[islot]] = c1a[r];
                Pd[list[islot]] = pda[r];
            }
        }
    }
}

// DMA one 32x256 bf16 tile into LDS (linear dest, source pre-swizzled so the
// read-side XOR sees conflict-free layout). 4 x 16B per thread.
__device__ __forceinline__ void stage_tile(const unsigned short* __restrict__ Bg,
                                           unsigned short* buf, int colBase, int tid) {
    #pragma unroll
    for (int it = 0; it < 4; ++it) {
        int c = it * 256 + tid;          // 16B-chunk index, 0..1023
        int brow = c >> 5, bc = c & 31;
        int sc = bc ^ (brow & 7);        // inverse swizzle on SOURCE
        const unsigned short* src = Bg + (size_t)(colBase + brow) * DDIM + sc * 8;
        __builtin_amdgcn_global_load_lds(
            (const __attribute__((address_space(1))) void*)src,
            (__attribute__((address_space(3))) void*)(buf + (size_t)c * 8),
            16, 0, 0);
    }
}

// K3: Gram + plain exp-sum over ALL columns (no labels, diag included).
// Grid (32 row-blocks, 16 chunks) = 512 blocks; wave owns 64 rows.
__global__ __launch_bounds__(256, 2) void supcon_main(
    const unsigned short* __restrict__ Bg, float* __restrict__ pSe)
{
    __shared__ alignas(16) unsigned short btile[2][TILE_COLS * DDIM];  // 2 x 16 KB

    const int tid = threadIdx.x;
    const int wid = tid >> 6;
    const int lane = tid & 63;
    const int q = lane >> 4;
    const int r16 = lane & 15;

    const int rowBase = blockIdx.x * 256 + wid * 64;   // wave owns 64 rows
    const int colChunk = blockIdx.y * CHUNK_COLS;

    // A fragments: 64 rows x K=256 in registers (128 VGPR).
    bf16x8 afr[4][8];
    #pragma unroll
    for (int m = 0; m < 4; ++m) {
        const unsigned short* ap = Bg + (size_t)(rowBase + m * 16 + r16) * DDIM + q * 8;
        #pragma unroll
        for (int ks = 0; ks < 8; ++ks)
            afr[m][ks] = *(const bf16x8*)(ap + ks * 32);
    }

    float se[4][4];
    #pragma unroll
    for (int m = 0; m < 4; ++m)
        #pragma unroll
        for (int r = 0; r < 4; ++r) se[m][r] = 0.f;

    stage_tile(Bg, btile[0], colChunk, tid);
    __syncthreads();   // drains vmcnt -> tile 0 ready

    for (int tile = 0; tile < NT; ++tile) {
        if (tile + 1 < NT)
            stage_tile(Bg, btile[(tile + 1) & 1], colChunk + (tile + 1) * TILE_COLS, tid);

        const unsigned short* bt = btile[tile & 1];
        f32x4 acc[4][2];
        #pragma unroll
        for (int m = 0; m < 4; ++m) { acc[m][0] = (f32x4)0.f; acc[m][1] = (f32x4)0.f; }

        __builtin_amdgcn_s_setprio(1);
        #pragma unroll
        for (int ks = 0; ks < 8; ++ks) {
            const int cx = (ks * 4 + q) ^ (r16 & 7);
            bf16x8 bq0 = *(const bf16x8*)(bt + r16 * DDIM + cx * 8);
            bf16x8 bq1 = *(const bf16x8*)(bt + (16 + r16) * DDIM + cx * 8);
            #pragma unroll
            for (int m = 0; m < 4; ++m) {
                acc[m][0] = __builtin_amdgcn_mfma_f32_16x16x32_bf16(afr[m][ks], bq0, acc[m][0], 0, 0, 0);
                acc[m][1] = __builtin_amdgcn_mfma_f32_16x16x32_bf16(afr[m][ks], bq1, acc[m][1], 0, 0, 0);
            }
        }
        __builtin_amdgcn_s_setprio(0);

        // thin epilogue: se += exp2(K1 * g) for every element
        #pragma unroll
        for (int n = 0; n < 2; ++n)
            #pragma unroll
            for (int m = 0; m < 4; ++m)
                #pragma unroll
                for (int r = 0; r < 4; ++r)
                    se[m][r] += __builtin_amdgcn_exp2f(acc[m][n][r] * K1);

        __syncthreads();   // drains DMA (next tile ready) + LDS reads done
    }

    // merge the 16 lanes (r16 bits) sharing each row
    #pragma unroll
    for (int mask = 1; mask <= 8; mask <<= 1)
        #pragma unroll
        for (int m = 0; m < 4; ++m)
            #pragma unroll
            for (int r = 0; r < 4; ++r)
                se[m][r] += __shfl_xor(se[m][r], mask);
    if (r16 == 0) {
        #pragma unroll
        for (int m = 0; m < 4; ++m) {
            const size_t o = (size_t)blockIdx.y * NTOT + rowBase + m * 16 + q * 4;
            f32x4 vs;
            #pragma unroll
            for (int r = 0; r < 4; ++r) vs[r] = se[m][r];
            *(f32x4*)(pSe + o) = vs;
        }
    }
}

// K4: per-row loss from (se_all, corrections) + block partial + atomic out.
__global__ __launch_bounds__(256) void finalize_kernel(
    const int* __restrict__ labT, const float* __restrict__ pSe,
    const float* __restrict__ C1, const float* __restrict__ Pd,
    const float* __restrict__ SelfE, float* __restrict__ out)
{
    __shared__ int hist[NCLASS];
    const int t = threadIdx.x;
    if (t < NCLASS) hist[t] = 0;
    __syncthreads();
    #pragma unroll
    for (int i = 0; i < NTOT / 256; ++i)
        atomicAdd(&hist[labT[i * 256 + t]], 1);
    __syncthreads();

    const int row = blockIdx.x * 256 + t;
    const int lab = labT[row];
    float se = 0.f;
    #pragma unroll
    for (int ch = 0; ch < NCHUNK; ++ch) se += pSe[(size_t)ch * NTOT + row];
    se = se - SelfE[row] - ONE_M_2B * C1[row];

    const float pc = (float)(hist[lab] - 1);
    float loss = EPI_T + __logf(se) - INV_T * Pd[row] / pc;

    #pragma unroll
    for (int mask = 1; mask < 64; mask <<= 1) loss += __shfl_xor(loss, mask);
    __shared__ float red[4];
    if ((t & 63) == 0) red[t >> 6] = loss;
    __syncthreads();
    if (t == 0)
        atomicAdd(out, (red[0] + red[1] + red[2] + red[3]) * (1.f / (float)NTOT));
}

extern "C" void kernel_launch(void* const* d_in, const int* in_sizes, int n_in,
                              void* d_out, int out_size, void* d_ws, size_t ws_size,
                              hipStream_t stream) {
    const float* feat = (const float*)d_in[0];
    const int* labels = (const int*)d_in[1];
    float* out = (float*)d_out;

    char* ws = (char*)d_ws;
    unsigned short* Bg = (unsigned short*)ws;                        // 4 MB
    int* labT = (int*)(ws + (4u << 20));                             // 32 KB
    float* pSe = (float*)(ws + (4u << 20) + (64u << 10));            // 512 KB
    float* C1v = (float*)(ws + (4u << 20) + (576u << 10));           // 32 KB
    float* Pdv = (float*)(ws + (4u << 20) + (640u << 10));           // 32 KB
    float* SEv = (float*)(ws + (4u << 20) + (704u << 10));           // 32 KB

    prep_kernel<<<2048, 256, 0, stream>>>(feat, labels, Bg, labT, out);
    dim3 cgrid(NCLASS, 4);
    classcorr_kernel<<<cgrid, 256, 0, stream>>>(Bg, labT, C1v, Pdv, SEv);
    dim3 grid(32, NCHUNK);
    supcon_main<<<grid, 256, 0, stream>>>(Bg, pSe);
    finalize_kernel<<<32, 256, 0, stream>>>(labT, pSe, C1v, Pdv, SEv, out);
}